// Round 1
// baseline (98.220 us; speedup 1.0000x reference)
//
#include <hip/hip_runtime.h>
#include <math.h>

#define H 1024
#define S 20
#define V 50257

__device__ __forceinline__ float wave_reduce_sum(float v) {
  #pragma unroll
  for (int off = 32; off > 0; off >>= 1)
    v += __shfl_xor(v, off, 64);
  return v;
}

__device__ __forceinline__ float wave_reduce_max(float v) {
  #pragma unroll
  for (int off = 32; off > 0; off >>= 1)
    v = fmaxf(v, __shfl_xor(v, off, 64));
  return v;
}

// K1: escore[s][j] = tanh(h_part[j] + enc_part[s][j] + attn_b[j]) * v_w[j]
// One wave per output row j (j in [0,H)). grid = H/4 blocks of 256.
__global__ __launch_bounds__(256) void k1_energy(
    const float* __restrict__ hidden,   // [H]
    const float* __restrict__ enc,      // [S*H]
    const float* __restrict__ attn_w,   // [H][2H]
    const float* __restrict__ attn_b,   // [H]
    const float* __restrict__ v_w,      // [H]
    float* __restrict__ escore)         // [S][H]
{
  const int lane = threadIdx.x & 63;
  const int wv = threadIdx.x >> 6;
  const int j = blockIdx.x * 4 + wv;

  const float* wrow = attn_w + (size_t)j * (2 * H);
  float4 wlo[4], whi[4], hid4[4];
  #pragma unroll
  for (int q = 0; q < 4; ++q) {
    const int idx = lane + 64 * q;
    wlo[q]  = ((const float4*)wrow)[idx];
    whi[q]  = ((const float4*)(wrow + H))[idx];
    hid4[q] = ((const float4*)hidden)[idx];
  }

  float hp = 0.f;
  #pragma unroll
  for (int q = 0; q < 4; ++q)
    hp += wlo[q].x * hid4[q].x + wlo[q].y * hid4[q].y +
          wlo[q].z * hid4[q].z + wlo[q].w * hid4[q].w;
  hp = wave_reduce_sum(hp);

  float myval = 0.f;
  #pragma unroll
  for (int s = 0; s < S; ++s) {
    const float4* e4 = (const float4*)(enc + s * H);
    float es = 0.f;
    #pragma unroll
    for (int q = 0; q < 4; ++q) {
      const int idx = lane + 64 * q;
      const float4 e = e4[idx];
      es += whi[q].x * e.x + whi[q].y * e.y + whi[q].z * e.z + whi[q].w * e.w;
    }
    es = wave_reduce_sum(es);
    if (lane == s) myval = es;
  }

  if (lane < S) {
    const float energy = tanhf(hp + myval + attn_b[j]);
    escore[lane * H + j] = energy * v_w[j];
  }
}

// K2: scores[s] = sum_j escore[s][j]; attn = softmax(scores);
//     weighted[h] = sum_s attn[s]*enc[s][h].  Single block of 256.
__global__ __launch_bounds__(256) void k2_softmax_weighted(
    const float* __restrict__ enc,
    const float* __restrict__ escore,
    float* __restrict__ weighted)
{
  __shared__ float red[4];
  __shared__ float scores[S];
  __shared__ float attn_s[S];
  const int t = threadIdx.x;
  const int lane = t & 63, wv = t >> 6;

  for (int s = 0; s < S; ++s) {
    float p = 0.f;
    for (int i = t; i < H; i += 256) p += escore[s * H + i];
    p = wave_reduce_sum(p);
    if (lane == 0) red[wv] = p;
    __syncthreads();
    if (t == 0) scores[s] = red[0] + red[1] + red[2] + red[3];
    __syncthreads();
  }

  if (t == 0) {
    float m = -1e30f;
    for (int s = 0; s < S; ++s) m = fmaxf(m, scores[s]);
    float sum = 0.f;
    for (int s = 0; s < S; ++s) {
      const float e = expf(scores[s] - m);
      attn_s[s] = e;
      sum += e;
    }
    const float inv = 1.f / sum;
    for (int s = 0; s < S; ++s) attn_s[s] *= inv;
  }
  __syncthreads();

  for (int h = t; h < H; h += 256) {
    float acc = 0.f;
    #pragma unroll
    for (int s = 0; s < S; ++s) acc += attn_s[s] * enc[s * H + h];
    weighted[h] = acc;
  }
}

// K3: fused GRU. One wave per output j: reads 3 rows of w_ih (len 2H) and
// 3 rows of w_hh (len H), computes gates and h_new[j].
__global__ __launch_bounds__(256) void k3_gru(
    const int* __restrict__ token,
    const float* __restrict__ embed_table, // [V][H]
    const float* __restrict__ weighted,    // [H]
    const float* __restrict__ hidden,      // [H]
    const float* __restrict__ w_ih,        // [3H][2H]
    const float* __restrict__ w_hh,        // [3H][H]
    const float* __restrict__ b_ih,        // [3H]
    const float* __restrict__ b_hh,        // [3H]
    float* __restrict__ hnew_ws,           // [H]
    float* __restrict__ out_hnew)          // d_out + V
{
  const int lane = threadIdx.x & 63;
  const int wv = threadIdx.x >> 6;
  const int j = blockIdx.x * 4 + wv;

  const float* embed = embed_table + (size_t)(*token) * H;

  float4 x4[8], h4[4];
  #pragma unroll
  for (int q = 0; q < 4; ++q) {
    const int idx = lane + 64 * q;
    x4[q]     = ((const float4*)embed)[idx];
    x4[q + 4] = ((const float4*)weighted)[idx];
    h4[q]     = ((const float4*)hidden)[idx];
  }

  float gi[3], gh[3];
  #pragma unroll
  for (int g = 0; g < 3; ++g) {
    const float4* wi = (const float4*)(w_ih + (size_t)(g * H + j) * (2 * H));
    float a = 0.f;
    #pragma unroll
    for (int q = 0; q < 8; ++q) {
      const int idx = (q < 4) ? (lane + 64 * q) : (256 + lane + 64 * (q - 4));
      const float4 w = wi[idx];
      a += w.x * x4[q].x + w.y * x4[q].y + w.z * x4[q].z + w.w * x4[q].w;
    }
    gi[g] = wave_reduce_sum(a);

    const float4* wh = (const float4*)(w_hh + (size_t)(g * H + j) * H);
    float b = 0.f;
    #pragma unroll
    for (int q = 0; q < 4; ++q) {
      const float4 w = wh[lane + 64 * q];
      b += w.x * h4[q].x + w.y * h4[q].y + w.z * h4[q].z + w.w * h4[q].w;
    }
    gh[g] = wave_reduce_sum(b);
  }

  if (lane == 0) {
    const float i_r = gi[0] + b_ih[j];
    const float i_z = gi[1] + b_ih[H + j];
    const float i_n = gi[2] + b_ih[2 * H + j];
    const float h_r = gh[0] + b_hh[j];
    const float h_z = gh[1] + b_hh[H + j];
    const float h_n = gh[2] + b_hh[2 * H + j];
    const float r = 1.f / (1.f + expf(-(i_r + h_r)));
    const float z = 1.f / (1.f + expf(-(i_z + h_z)));
    const float n = tanhf(i_n + r * h_n);
    const float hn = (1.f - z) * n + z * hidden[j];
    hnew_ws[j] = hn;
    out_hnew[j] = hn;
  }
}

// K5: logits[v] = dot(out_w[v], hnew) + out_b[v]; per-block max -> pmax.
__global__ __launch_bounds__(256) void k5_logits(
    const float* __restrict__ hnew,
    const float* __restrict__ out_w,   // [V][H]
    const float* __restrict__ out_b,   // [V]
    float* __restrict__ logits,        // d_out (first V)
    float* __restrict__ pmax)
{
  __shared__ float wmax[4];
  const int lane = threadIdx.x & 63;
  const int wv = threadIdx.x >> 6;
  const int v = blockIdx.x * 4 + wv;

  float val = -INFINITY;
  if (v < V) {
    const float4* wr = (const float4*)(out_w + (size_t)v * H);
    float a = 0.f;
    #pragma unroll
    for (int q = 0; q < 4; ++q) {
      const int idx = lane + 64 * q;
      const float4 w = wr[idx];
      const float4 h = ((const float4*)hnew)[idx];
      a += w.x * h.x + w.y * h.y + w.z * h.z + w.w * h.w;
    }
    a = wave_reduce_sum(a);
    val = a + out_b[v];
    if (lane == 0) logits[v] = val;
  }
  if (lane == 0) wmax[wv] = val;
  __syncthreads();
  if (threadIdx.x == 0)
    pmax[blockIdx.x] = fmaxf(fmaxf(wmax[0], wmax[1]), fmaxf(wmax[2], wmax[3]));
}

// K6: M = max(pmax); logS = log(sum(exp(logits - M))). Single block 1024.
__global__ __launch_bounds__(1024) void k6_reduce(
    const float* __restrict__ logits,
    const float* __restrict__ pmax, int npmax,
    float* __restrict__ red)           // red[0]=M, red[1]=logS
{
  __shared__ float lds[16];
  __shared__ float lds2[16];
  __shared__ float Msh;
  const int t = threadIdx.x, lane = t & 63, wv = t >> 6;

  float m = -INFINITY;
  for (int i = t; i < npmax; i += 1024) m = fmaxf(m, pmax[i]);
  m = wave_reduce_max(m);
  if (lane == 0) lds[wv] = m;
  __syncthreads();
  if (t == 0) {
    float mm = lds[0];
    for (int w = 1; w < 16; ++w) mm = fmaxf(mm, lds[w]);
    Msh = mm;
  }
  __syncthreads();
  const float M = Msh;

  float s = 0.f;
  for (int i = t; i < V; i += 1024) s += expf(logits[i] - M);
  s = wave_reduce_sum(s);
  if (lane == 0) lds2[wv] = s;
  __syncthreads();
  if (t == 0) {
    float ss = 0.f;
    for (int w = 0; w < 16; ++w) ss += lds2[w];
    red[0] = M;
    red[1] = logf(ss);
  }
}

// K7: out[v] = logits[v] - (M + logS)
__global__ __launch_bounds__(256) void k7_final(
    float* __restrict__ logits, const float* __restrict__ red)
{
  const int i = blockIdx.x * 256 + threadIdx.x;
  if (i < V) logits[i] -= (red[0] + red[1]);
}

extern "C" void kernel_launch(void* const* d_in, const int* in_sizes, int n_in,
                              void* d_out, int out_size, void* d_ws, size_t ws_size,
                              hipStream_t stream) {
  const int*   token       = (const int*)d_in[0];
  const float* hidden      = (const float*)d_in[1];
  const float* enc         = (const float*)d_in[2];
  const float* embed_table = (const float*)d_in[3];
  const float* attn_w      = (const float*)d_in[4];
  const float* attn_b      = (const float*)d_in[5];
  const float* v_w         = (const float*)d_in[6];
  const float* w_ih        = (const float*)d_in[7];
  const float* w_hh        = (const float*)d_in[8];
  const float* b_ih        = (const float*)d_in[9];
  const float* b_hh        = (const float*)d_in[10];
  const float* out_w       = (const float*)d_in[11];
  const float* out_b       = (const float*)d_in[12];
  float* out = (float*)d_out;
  float* ws  = (float*)d_ws;

  // ws layout (floats)
  float* escore   = ws;            // S*H   = 20480
  float* weighted = ws + 20480;    // 1024
  float* hnew     = ws + 21504;    // 1024
  float* pmax     = ws + 22528;    // 12565 (padded 12576)
  float* red      = ws + 35104;    // 2

  const int nblk5 = (V + 3) / 4;   // 12565

  k1_energy<<<H / 4, 256, 0, stream>>>(hidden, enc, attn_w, attn_b, v_w, escore);
  k2_softmax_weighted<<<1, 256, 0, stream>>>(enc, escore, weighted);
  k3_gru<<<H / 4, 256, 0, stream>>>(token, embed_table, weighted, hidden,
                                    w_ih, w_hh, b_ih, b_hh, hnew, out + V);
  k5_logits<<<nblk5, 256, 0, stream>>>(hnew, out_w, out_b, out, pmax);
  k6_reduce<<<1, 1024, 0, stream>>>(out, pmax, nblk5, red);
  k7_final<<<(V + 255) / 256, 256, 0, stream>>>(out, red);
}

// Round 2
// 63.209 us; speedup vs baseline: 1.5539x; 1.5539x over previous
//
#include <hip/hip_runtime.h>
#include <math.h>

#define H 1024
#define S 20
#define V 50257

typedef float v4f __attribute__((ext_vector_type(4)));

__device__ __forceinline__ float wave_reduce_sum(float v) {
  #pragma unroll
  for (int off = 32; off > 0; off >>= 1)
    v += __shfl_xor(v, off, 64);
  return v;
}

__device__ __forceinline__ float wave_reduce_max(float v) {
  #pragma unroll
  for (int off = 32; off > 0; off >>= 1)
    v = fmaxf(v, __shfl_xor(v, off, 64));
  return v;
}

// K1: wave per attention row j. Computes escore[s][j] = tanh(hp + ep_s + b[j])*v_w[j]
// for s=0..19, then block-reduces over its 4 j's into bpart[s*256 + blockIdx].
__global__ __launch_bounds__(256) void k1_energy(
    const float* __restrict__ hidden,   // [H]
    const float* __restrict__ enc,      // [S*H]
    const float* __restrict__ attn_w,   // [H][2H]
    const float* __restrict__ attn_b,   // [H]
    const float* __restrict__ v_w,      // [H]
    float* __restrict__ bpart)          // [S][256]
{
  __shared__ float esh[4][S];
  const int lane = threadIdx.x & 63;
  const int wv = threadIdx.x >> 6;
  const int j = blockIdx.x * 4 + wv;

  const float* wrow = attn_w + (size_t)j * (2 * H);
  float4 wlo[4], whi[4], hid4[4];
  #pragma unroll
  for (int q = 0; q < 4; ++q) {
    const int idx = lane + 64 * q;
    wlo[q]  = ((const float4*)wrow)[idx];
    whi[q]  = ((const float4*)(wrow + H))[idx];
    hid4[q] = ((const float4*)hidden)[idx];
  }

  float hp = 0.f;
  #pragma unroll
  for (int q = 0; q < 4; ++q)
    hp += wlo[q].x * hid4[q].x + wlo[q].y * hid4[q].y +
          wlo[q].z * hid4[q].z + wlo[q].w * hid4[q].w;
  hp = wave_reduce_sum(hp);

  float myval = 0.f;
  #pragma unroll
  for (int s = 0; s < S; ++s) {
    const float4* e4 = (const float4*)(enc + s * H);
    float es = 0.f;
    #pragma unroll
    for (int q = 0; q < 4; ++q) {
      const int idx = lane + 64 * q;
      const float4 e = e4[idx];
      es += whi[q].x * e.x + whi[q].y * e.y + whi[q].z * e.z + whi[q].w * e.w;
    }
    es = wave_reduce_sum(es);
    if (lane == s) myval = es;
  }

  if (lane < S)
    esh[wv][lane] = tanhf(hp + myval + attn_b[j]) * v_w[j];
  __syncthreads();
  if (wv == 0 && lane < S)
    bpart[lane * 256 + blockIdx.x] =
        esh[0][lane] + esh[1][lane] + esh[2][lane] + esh[3][lane];
}

// K3: fused scores-reduce + softmax + context + GRU.
__global__ __launch_bounds__(256) void k3_gru(
    const int* __restrict__ token,
    const float* __restrict__ embed_table, // [V][H]
    const float* __restrict__ bpart,       // [S][256]
    const float* __restrict__ enc,         // [S*H]
    const float* __restrict__ hidden,      // [H]
    const float* __restrict__ w_ih,        // [3H][2H]
    const float* __restrict__ w_hh,        // [3H][H]
    const float* __restrict__ b_ih,        // [3H]
    const float* __restrict__ b_hh,        // [3H]
    float* __restrict__ hnew_ws,           // [H]
    float* __restrict__ out_hnew)          // d_out + V
{
  __shared__ float scores_sh[S];
  __shared__ float attn_s[S];
  __shared__ float wsh[H];                 // context vector, 4KB
  const int t = threadIdx.x;
  const int lane = t & 63;
  const int wv = t >> 6;
  const int j = blockIdx.x * 4 + wv;

  // phase 0: reduce bpart -> scores (wave wv handles s = wv, wv+4, ...)
  for (int s = wv; s < S; s += 4) {
    const float4 p = ((const float4*)(bpart + s * 256))[lane];
    float v = p.x + p.y + p.z + p.w;
    v = wave_reduce_sum(v);
    if (lane == 0) scores_sh[s] = v;
  }
  __syncthreads();
  if (t == 0) {
    float m = -1e30f;
    for (int s = 0; s < S; ++s) m = fmaxf(m, scores_sh[s]);
    float sum = 0.f;
    for (int s = 0; s < S; ++s) {
      const float e = expf(scores_sh[s] - m);
      attn_s[s] = e;
      sum += e;
    }
    const float inv = 1.f / sum;
    for (int s = 0; s < S; ++s) attn_s[s] *= inv;
  }
  __syncthreads();

  // phase 1: context vector into LDS
  for (int h = t; h < H; h += 256) {
    float acc = 0.f;
    #pragma unroll
    for (int s = 0; s < S; ++s) acc += attn_s[s] * enc[s * H + h];
    wsh[h] = acc;
  }
  __syncthreads();

  // phase 2: GRU, wave per output j
  const float* embed = embed_table + (size_t)(*token) * H;
  float4 x4[8], h4[4];
  #pragma unroll
  for (int q = 0; q < 4; ++q) {
    const int idx = lane + 64 * q;
    x4[q]     = ((const float4*)embed)[idx];
    x4[q + 4] = ((const float4*)wsh)[idx];
    h4[q]     = ((const float4*)hidden)[idx];
  }

  float gi[3], gh[3];
  #pragma unroll
  for (int g = 0; g < 3; ++g) {
    const float4* wi = (const float4*)(w_ih + (size_t)(g * H + j) * (2 * H));
    float a = 0.f;
    #pragma unroll
    for (int q = 0; q < 8; ++q) {
      const int idx = (q < 4) ? (lane + 64 * q) : (256 + lane + 64 * (q - 4));
      const float4 w = wi[idx];
      a += w.x * x4[q].x + w.y * x4[q].y + w.z * x4[q].z + w.w * x4[q].w;
    }
    gi[g] = wave_reduce_sum(a);

    const float4* wh = (const float4*)(w_hh + (size_t)(g * H + j) * H);
    float b = 0.f;
    #pragma unroll
    for (int q = 0; q < 4; ++q) {
      const float4 w = wh[lane + 64 * q];
      b += w.x * h4[q].x + w.y * h4[q].y + w.z * h4[q].z + w.w * h4[q].w;
    }
    gh[g] = wave_reduce_sum(b);
  }

  if (lane == 0) {
    const float i_r = gi[0] + b_ih[j];
    const float i_z = gi[1] + b_ih[H + j];
    const float i_n = gi[2] + b_ih[2 * H + j];
    const float h_r = gh[0] + b_hh[j];
    const float h_z = gh[1] + b_hh[H + j];
    const float h_n = gh[2] + b_hh[2 * H + j];
    const float r = 1.f / (1.f + expf(-(i_r + h_r)));
    const float z = 1.f / (1.f + expf(-(i_z + h_z)));
    const float n = tanhf(i_n + r * h_n);
    const float hn = (1.f - z) * n + z * hidden[j];
    hnew_ws[j] = hn;
    out_hnew[j] = hn;
  }
}

// K5: 2 rows per wave. logits + per-block online-softmax stats (max, sum-exp).
__global__ __launch_bounds__(256) void k5_logits(
    const float* __restrict__ hnew,
    const float* __restrict__ out_w,   // [V][H]
    const float* __restrict__ out_b,   // [V]
    float* __restrict__ logits,        // d_out (first V)
    float* __restrict__ pmax,
    float* __restrict__ psum)
{
  __shared__ float vals[8];
  const int lane = threadIdx.x & 63;
  const int wv = threadIdx.x >> 6;
  const int v0 = (blockIdx.x * 4 + wv) * 2;
  const int v1 = v0 + 1;

  float4 h4[4];
  #pragma unroll
  for (int q = 0; q < 4; ++q)
    h4[q] = ((const float4*)hnew)[lane + 64 * q];

  float val0 = -INFINITY, val1 = -INFINITY;
  if (v0 < V) {
    const v4f* r0 = (const v4f*)(out_w + (size_t)v0 * H);
    const v4f* r1 = (const v4f*)(out_w + (size_t)v1 * H);  // may be OOB row only if v1>=V; guarded below
    float a0 = 0.f, a1 = 0.f;
    if (v1 < V) {
      #pragma unroll
      for (int q = 0; q < 4; ++q) {
        const int idx = lane + 64 * q;
        const v4f w0 = __builtin_nontemporal_load(r0 + idx);
        const v4f w1 = __builtin_nontemporal_load(r1 + idx);
        a0 += w0.x * h4[q].x + w0.y * h4[q].y + w0.z * h4[q].z + w0.w * h4[q].w;
        a1 += w1.x * h4[q].x + w1.y * h4[q].y + w1.z * h4[q].z + w1.w * h4[q].w;
      }
    } else {
      #pragma unroll
      for (int q = 0; q < 4; ++q) {
        const int idx = lane + 64 * q;
        const v4f w0 = __builtin_nontemporal_load(r0 + idx);
        a0 += w0.x * h4[q].x + w0.y * h4[q].y + w0.z * h4[q].z + w0.w * h4[q].w;
      }
    }
    a0 = wave_reduce_sum(a0);
    a1 = wave_reduce_sum(a1);
    val0 = a0 + out_b[v0];
    if (lane == 0) logits[v0] = val0;
    if (v1 < V) {
      val1 = a1 + out_b[v1];
      if (lane == 0) logits[v1] = val1;
    }
  }
  if (lane == 0) {
    vals[wv * 2]     = val0;
    vals[wv * 2 + 1] = val1;
  }
  __syncthreads();
  if (threadIdx.x == 0) {
    float m = -INFINITY;
    #pragma unroll
    for (int i = 0; i < 8; ++i) m = fmaxf(m, vals[i]);
    float s = 0.f;
    #pragma unroll
    for (int i = 0; i < 8; ++i) s += expf(vals[i] - m);
    pmax[blockIdx.x] = m;
    psum[blockIdx.x] = s;
  }
}

// K6: combine per-block stats -> red[0]=M, red[1]=logS. Single block 1024.
__global__ __launch_bounds__(1024) void k6_reduce(
    const float* __restrict__ pmax,
    const float* __restrict__ psum, int n,
    float* __restrict__ red)
{
  __shared__ float lds[16];
  __shared__ float lds2[16];
  __shared__ float Msh;
  const int t = threadIdx.x, lane = t & 63, wv = t >> 6;

  float m = -INFINITY;
  for (int i = t; i < n; i += 1024) m = fmaxf(m, pmax[i]);
  m = wave_reduce_max(m);
  if (lane == 0) lds[wv] = m;
  __syncthreads();
  if (t == 0) {
    float mm = lds[0];
    for (int w = 1; w < 16; ++w) mm = fmaxf(mm, lds[w]);
    Msh = mm;
  }
  __syncthreads();
  const float M = Msh;

  float s = 0.f;
  for (int i = t; i < n; i += 1024) s += psum[i] * expf(pmax[i] - M);
  s = wave_reduce_sum(s);
  if (lane == 0) lds2[wv] = s;
  __syncthreads();
  if (t == 0) {
    float ss = 0.f;
    for (int w = 0; w < 16; ++w) ss += lds2[w];
    red[0] = M;
    red[1] = logf(ss);
  }
}

// K7: out[v] = logits[v] - (M + logS)
__global__ __launch_bounds__(256) void k7_final(
    float* __restrict__ logits, const float* __restrict__ red)
{
  const int i = blockIdx.x * 256 + threadIdx.x;
  if (i < V) logits[i] -= (red[0] + red[1]);
}

extern "C" void kernel_launch(void* const* d_in, const int* in_sizes, int n_in,
                              void* d_out, int out_size, void* d_ws, size_t ws_size,
                              hipStream_t stream) {
  const int*   token       = (const int*)d_in[0];
  const float* hidden      = (const float*)d_in[1];
  const float* enc         = (const float*)d_in[2];
  const float* embed_table = (const float*)d_in[3];
  const float* attn_w      = (const float*)d_in[4];
  const float* attn_b      = (const float*)d_in[5];
  const float* v_w         = (const float*)d_in[6];
  const float* w_ih        = (const float*)d_in[7];
  const float* w_hh        = (const float*)d_in[8];
  const float* b_ih        = (const float*)d_in[9];
  const float* b_hh        = (const float*)d_in[10];
  const float* out_w       = (const float*)d_in[11];
  const float* out_b       = (const float*)d_in[12];
  float* out = (float*)d_out;
  float* ws  = (float*)d_ws;

  // ws layout (floats)
  float* bpart = ws;            // S*256 = 5120
  float* hnew  = ws + 5120;     // 1024
  float* pmax  = ws + 6144;     // 6283 (pad 6400)
  float* psum  = ws + 12544;    // 6283 (pad 6400)
  float* red   = ws + 18944;    // 2

  const int nblk5 = (V + 7) / 8;   // 6283 blocks, 8 rows each

  k1_energy<<<H / 4, 256, 0, stream>>>(hidden, enc, attn_w, attn_b, v_w, bpart);
  k3_gru<<<H / 4, 256, 0, stream>>>(token, embed_table, bpart, enc, hidden,
                                    w_ih, w_hh, b_ih, b_hh, hnew, out + V);
  k5_logits<<<nblk5, 256, 0, stream>>>(hnew, out_w, out_b, out, pmax, psum);
  k6_reduce<<<1, 1024, 0, stream>>>(pmax, psum, nblk5, red);
  k7_final<<<(V + 255) / 256, 256, 0, stream>>>(out, red);
}